// Round 9
// baseline (10598.178 us; speedup 1.0000x reference)
//
#include <hip/hip_runtime.h>

typedef unsigned short u16;
typedef unsigned int u32;
typedef unsigned long long u64;
typedef __attribute__((ext_vector_type(8))) short bf16x8;
typedef __attribute__((ext_vector_type(4))) float f32x4;

#define SMEM_SCAN 147968

__device__ __forceinline__ u16 f2bf(float f) {
  u32 u = __float_as_uint(f);
  u += 0x7fffu + ((u >> 16) & 1u);
  return (u16)(u >> 16);
}

__device__ __forceinline__ void async16(const void* g, void* l) {
  __builtin_amdgcn_global_load_lds((const __attribute__((address_space(1))) void*)g,
                                   (__attribute__((address_space(3))) void*)l, 16, 0, 0);
}

// relaxed agent-scope write-through stores: visible at coherence point once
// vmcnt drains (at __syncthreads), never leave dirty L2 lines.
__device__ __forceinline__ void st_f32(float* p, float v) {
  __hip_atomic_store(p, v, __ATOMIC_RELAXED, __HIP_MEMORY_SCOPE_AGENT);
}
__device__ __forceinline__ void st_u16(u16* p, u16 v) {
  __hip_atomic_store(p, v, __ATOMIC_RELAXED, __HIP_MEMORY_SCOPE_AGENT);
}
__device__ __forceinline__ void st_f32x2(float* p, float a, float b) {
  u64 v = ((u64)__float_as_uint(b) << 32) | (u64)__float_as_uint(a);
  __hip_atomic_store((u64*)p, v, __ATOMIC_RELAXED, __HIP_MEMORY_SCOPE_AGENT);
}
__device__ __forceinline__ u32 ld_u32(const u32* p) {
  return __hip_atomic_load(p, __ATOMIC_RELAXED, __HIP_MEMORY_SCOPE_AGENT);
}

// ---------------- doorbell sync (no barrier, no checker relay) ----------------
// Post: after __syncthreads drains this WG's write-through stores, tid0 stores
// db[wid]=tag. Wait: wave 0 polls all 128 slots (2 uncached loads/lane + __all),
// then ONE acquire fence (buffer_inv), then __syncthreads; bulk reads are cached.
__device__ __forceinline__ void db_post(u32* db, int wid, u32 tag) {
  __syncthreads();   // all waves' data stores at coherence point
  if (threadIdx.x == 0)
    __hip_atomic_store(db + wid, tag, __ATOMIC_RELAXED, __HIP_MEMORY_SCOPE_AGENT);
}
__device__ __forceinline__ void db_wait(const u32* db, u32 tag) {
  const int tid = threadIdx.x;
  if (tid < 64) {
    const u32* a0 = db + tid;
    const u32* a1 = db + 64 + tid;
    for (;;) {
      u32 v0 = ld_u32(a0);
      u32 v1 = ld_u32(a1);
      if (__all((v0 >= tag) && (v1 >= tag))) break;
      __builtin_amdgcn_s_sleep(4);
    }
    if (tid == 0) __builtin_amdgcn_fence(__ATOMIC_ACQUIRE, "agent");
  }
  __syncthreads();
}

// ---------------- embedding gather + LayerNorm -> f32 ----------------
__global__ void __launch_bounds__(256)
k_embed_f32(const int* __restrict__ ids, const float* __restrict__ emb,
            const float* __restrict__ g, const float* __restrict__ b, float* __restrict__ tok) {
  int r = blockIdx.x;            // r = t*8 + batch
  int s = r >> 3, bch = r & 7;
  int id = ids[bch * 512 + s];
  const float* row = emb + (size_t)id * 512;
  int tid = threadIdx.x;
  float2 v = *(const float2*)&row[tid * 2];
  float sum = v.x + v.y, sq = v.x * v.x + v.y * v.y;
  #pragma unroll
  for (int o = 1; o < 64; o <<= 1) { sum += __shfl_xor(sum, o); sq += __shfl_xor(sq, o); }
  __shared__ float rs[4][2];
  int w = tid >> 6;
  if ((tid & 63) == 0) { rs[w][0] = sum; rs[w][1] = sq; }
  __syncthreads();
  float S = rs[0][0] + rs[1][0] + rs[2][0] + rs[3][0];
  float Q = rs[0][1] + rs[1][1] + rs[2][1] + rs[3][1];
  float m = S * (1.f / 512.f);
  float rstd = rsqrtf(Q * (1.f / 512.f) - m * m + 1e-5f);
  int e = tid * 2;
  float2 o2;
  o2.x = (v.x - m) * rstd * g[e] + b[e];
  o2.y = (v.y - m) * rstd * g[e + 1] + b[e + 1];
  *(float2*)&tok[(size_t)r * 512 + e] = o2;
}

// ---------------- f32 [K][N] -> bf16 [N][K] transpose-convert ----------------
__global__ void __launch_bounds__(256)
k_transpose(const float* __restrict__ src, u16* __restrict__ dst,
            int K, int N, int stride) {
  __shared__ float tl[64][65];
  int k0 = blockIdx.x << 6, n0 = blockIdx.y << 6;
  int tid = threadIdx.x;
  int a = tid >> 6, c = tid & 63;
  #pragma unroll
  for (int p = 0; p < 64; p += 4)
    tl[p + a][c] = src[(size_t)(k0 + p + a) * stride + n0 + c];
  __syncthreads();
  #pragma unroll
  for (int p = 0; p < 64; p += 4)
    dst[(size_t)(n0 + p + a) * K + k0 + c] = f2bf(tl[c][p + a]);
}

// ---------------- f32 [K][N] -> f32 [N][K] transpose ----------------
__global__ void __launch_bounds__(256)
k_transpose_f32(const float* __restrict__ src, float* __restrict__ dst,
                int K, int N, int stride) {
  __shared__ float tl[64][65];
  int k0 = blockIdx.x << 6, n0 = blockIdx.y << 6;
  int tid = threadIdx.x;
  int a = tid >> 6, c = tid & 63;
  #pragma unroll
  for (int p = 0; p < 64; p += 4)
    tl[p + a][c] = src[(size_t)(k0 + p + a) * stride + n0 + c];
  __syncthreads();
  #pragma unroll
  for (int p = 0; p < 64; p += 4)
    dst[(size_t)(n0 + p + a) * K + k0 + c] = tl[c][p + a];
}

// ---------------- naive f32 tiled GEMM: C[m][n] = A[m]·BT[n] + bias[n] ----------------
__global__ void __launch_bounds__(256)
k_gemm_f32(const float* __restrict__ A, const float* __restrict__ BT,
           const float* __restrict__ bias, float* __restrict__ C, int K, int N) {
  __shared__ float Atl[64][17];
  __shared__ float Btl[64][17];
  int tid = threadIdx.x;
  int m0 = blockIdx.x << 6, n0 = blockIdx.y << 6;
  int lr = tid >> 2, lk = (tid & 3) << 2;
  int tm = (tid >> 4) << 2, tn = (tid & 15) << 2;
  float acc[4][4] = {{0.f}};
  for (int k0 = 0; k0 < K; k0 += 16) {
    float4 av = *(const float4*)&A[(size_t)(m0 + lr) * K + k0 + lk];
    float4 bv = *(const float4*)&BT[(size_t)(n0 + lr) * K + k0 + lk];
    __syncthreads();
    Atl[lr][lk] = av.x; Atl[lr][lk + 1] = av.y; Atl[lr][lk + 2] = av.z; Atl[lr][lk + 3] = av.w;
    Btl[lr][lk] = bv.x; Btl[lr][lk + 1] = bv.y; Btl[lr][lk + 2] = bv.z; Btl[lr][lk + 3] = bv.w;
    __syncthreads();
    #pragma unroll
    for (int kk = 0; kk < 16; kk++) {
      float a0 = Atl[tm][kk], a1 = Atl[tm + 1][kk], a2 = Atl[tm + 2][kk], a3 = Atl[tm + 3][kk];
      float b0 = Btl[tn][kk], b1 = Btl[tn + 1][kk], b2 = Btl[tn + 2][kk], b3 = Btl[tn + 3][kk];
      acc[0][0] += a0 * b0; acc[0][1] += a0 * b1; acc[0][2] += a0 * b2; acc[0][3] += a0 * b3;
      acc[1][0] += a1 * b0; acc[1][1] += a1 * b1; acc[1][2] += a1 * b2; acc[1][3] += a1 * b3;
      acc[2][0] += a2 * b0; acc[2][1] += a2 * b1; acc[2][2] += a2 * b2; acc[2][3] += a2 * b3;
      acc[3][0] += a3 * b0; acc[3][1] += a3 * b1; acc[3][2] += a3 * b2; acc[3][3] += a3 * b3;
    }
  }
  #pragma unroll
  for (int a = 0; a < 4; a++)
    #pragma unroll
    for (int b = 0; b < 4; b++)
      C[(size_t)(m0 + tm + a) * N + n0 + tn + b] = acc[a][b] + bias[n0 + tn + b];
}

// ---------------- bf16 MFMA GEMM (logits): C = A[M,K] @ B[N,K]^T + bias, remapped ----------------
__global__ void __launch_bounds__(256)
k_gemm_logits(const u16* __restrict__ A, const u16* __restrict__ B,
              const float* __restrict__ bias, float* __restrict__ C, int K) {
  __shared__ u16 As[128 * 32];
  __shared__ u16 Bs[128 * 32];
  int tid = threadIdx.x;
  int w = tid >> 6, l = tid & 63;
  int m0 = blockIdx.x * 128, n0 = blockIdx.y * 128;
  const u16* pA0 = A + (size_t)(m0 + w * 32 + (l >> 2)) * K + (l & 3) * 8;
  const u16* pB0 = B + (size_t)(n0 + w * 32 + (l >> 2)) * K + (l & 3) * 8;
  u16* lA0 = As + w * 1024;
  u16* lB0 = Bs + w * 1024;

  f32x4 acc[4][4];
  #pragma unroll
  for (int i = 0; i < 4; i++)
    #pragma unroll
    for (int j = 0; j < 4; j++) { f32x4 z = {0.f, 0.f, 0.f, 0.f}; acc[i][j] = z; }

  #pragma unroll 1
  for (int k0 = 0; k0 < K; k0 += 32) {
    async16(pA0, lA0);
    async16(pA0 + 16 * K, lA0 + 512);
    async16(pB0, lB0);
    async16(pB0 + 16 * K, lB0 + 512);
    pA0 += 32; pB0 += 32;
    __syncthreads();
    bf16x8 a[4], b[4];
    #pragma unroll
    for (int i = 0; i < 4; i++)
      a[i] = *(const bf16x8*)(As + ((w & 1) * 64 + i * 16 + (l & 15)) * 32 + (l >> 4) * 8);
    #pragma unroll
    for (int j = 0; j < 4; j++)
      b[j] = *(const bf16x8*)(Bs + ((w >> 1) * 64 + j * 16 + (l & 15)) * 32 + (l >> 4) * 8);
    #pragma unroll
    for (int i = 0; i < 4; i++)
      #pragma unroll
      for (int j = 0; j < 4; j++)
        acc[i][j] = __builtin_amdgcn_mfma_f32_16x16x32_bf16(a[i], b[j], acc[i][j], 0, 0, 0);
    __syncthreads();
  }

  #pragma unroll
  for (int j = 0; j < 4; j++) {
    int gn = n0 + (w >> 1) * 64 + j * 16 + (l & 15);
    float bj = bias[gn];
    #pragma unroll
    for (int i = 0; i < 4; i++) {
      int gmB = m0 + (w & 1) * 64 + i * 16 + (l >> 4) * 4;
      #pragma unroll
      for (int e = 0; e < 4; e++) {
        int gm = gmB + e;   // gm = t*8 + b  ->  logits[(b*512 + t)*32000 + gn]
        C[(size_t)((gm & 7) * 512 + (gm >> 3)) * 32000 + gn] = acc[i][j][e] + bj;
      }
    }
  }
}

// ---------------- persistent dataflow recurrence kernel ----------------
// 128 WGs x 512 threads, 1 WG/CU, LDS-resident f32 weights. Cross-WG state is
// double-buffered (h1f/h2f/pre_ctx: products of step t in buffer t&1); sync is
// per-phase doorbells (db_h1/db_h2/db_ctx, tag = t+1), all-poll + one acquire
// fence, cached bulk reads. No grid barrier anywhere.
__global__ void __launch_bounds__(512)
k_scan(const float* __restrict__ W1cT, const float* __restrict__ W2T,
       const float* __restrict__ WgcT, const float* __restrict__ WccT,
       const float* __restrict__ WghT, const float* __restrict__ WchT,
       const float* __restrict__ b2v, const float* __restrict__ bgv,
       const float* __restrict__ bcv, const float* __restrict__ cng,
       const float* __restrict__ cnb, const float* __restrict__ pre1,
       float* __restrict__ h1f, float* __restrict__ h2f,
       float* __restrict__ pre_ctx, u16* __restrict__ h2all,
       float* __restrict__ traj, u32* __restrict__ db) {
  extern __shared__ float smem[];
  float* w1   = smem;                 // [8][512]  h1 cols wid*8+g           (16 KB)
  float* wgc  = w1 + 4096;            // [8][512]  0-3 gate / 4-7 cand ctx   (16 KB)
  float* w2   = wgc + 4096;           // [8][1024] W2 cols wid*8+g           (32 KB)
  float* wgh  = w2 + 8192;            // [8][1024] 0-3 gate / 4-7 cand h2    (32 KB)
  float* ctxn = wgh + 8192;           // [8][512]  normalized ctx            (16 KB)
  float* hst  = ctxn + 4096;          // [8][1024] staged h1 / h2            (32 KB)
  float* gcc  = hst + 8192;           // [8][8]    ctx-part gate/cand dots
  float* pscr = gcc + 64;             // [8][8]    h2-part gate/cand dots

  u32* db_h1  = db;
  u32* db_h2  = db + 128;
  u32* db_ctx = db + 256;

  const int tid = threadIdx.x;
  const int wid = blockIdx.x;
  const int g   = tid >> 5;           // phase-1 group 0..15
  const int s   = tid & 31;
  const int gg  = tid >> 6;           // phase-2/3 group 0..7
  const int l   = tid & 63;

  // ---- one-time weight preload into LDS (all contiguous f32 slices) ----
  {
    const float4* srcs[6] = {
      (const float4*)(W1cT + (size_t)wid * 4096),
      (const float4*)(WgcT + (size_t)wid * 2048),
      (const float4*)(WccT + (size_t)wid * 2048),
      (const float4*)(W2T  + (size_t)wid * 8192),
      (const float4*)(WghT + (size_t)wid * 4096),
      (const float4*)(WchT + (size_t)wid * 4096)};
    float4* dsts[6] = {(float4*)w1, (float4*)wgc, (float4*)(wgc + 2048),
                       (float4*)w2, (float4*)wgh, (float4*)(wgh + 4096)};
    const int n4[6] = {1024, 512, 512, 2048, 1024, 1024};
    #pragma unroll
    for (int q = 0; q < 6; q++)
      for (int i = tid; i < n4[q]; i += 512) dsts[q][i] = srcs[q][i];
  }

  // ---- per-thread constant preloads ----
  const int l8 = l * 8;
  const float4 cga = *(const float4*)&cng[l8];
  const float4 cgb = *(const float4*)&cng[l8 + 4];
  const float4 cba = *(const float4*)&cnb[l8];
  const float4 cbb = *(const float4*)&cnb[l8 + 4];
  const float b2j = b2v[(wid << 3) + gg];
  float bgj = 0.f, bcj = 0.f;
  if (tid < 32) {
    int j = (wid << 2) + (tid >> 3);
    bgj = bgv[j]; bcj = bcv[j];
  }
  __syncthreads();

  #pragma unroll 1
  for (int t = 0; t < 512; ++t) {
    const float* ctx_rd = pre_ctx + (t & 1) * 4096;        // ctx for step t
    float*       ctx_wr = pre_ctx + ((t + 1) & 1) * 4096;  // ctx for step t+1
    const float* h1_rd  = h1f + (t & 1) * 8192;
    float*       h1_wr  = h1f + (t & 1) * 8192;
    const float* h2_rd  = h2f + (t & 1) * 8192;
    float*       h2_wr  = h2f + (t & 1) * 8192;

    // prefetch pre1 (read-only, written before launch: safe to load pre-fence)
    float pre1v = 0.f;
    if (g < 8 && s < 8)
      pre1v = pre1[(size_t)((t << 3) + s) * 1024 + (wid << 3) + g];

    // ===== phase 1: wait ctx(t); LN -> ctxn (redundant per WG); h1 + gc_ctx dots =====
    if (t > 0) {
      db_wait(db_ctx, (u32)t);
      const float* pr = ctx_rd + gg * 512 + l8;   // wave gg handles row gg
      float4 v0 = *(const float4*)pr;
      float4 v1 = *(const float4*)(pr + 4);
      float sum = v0.x + v0.y + v0.z + v0.w + v1.x + v1.y + v1.z + v1.w;
      float sq  = v0.x*v0.x + v0.y*v0.y + v0.z*v0.z + v0.w*v0.w
                + v1.x*v1.x + v1.y*v1.y + v1.z*v1.z + v1.w*v1.w;
      #pragma unroll
      for (int o = 1; o < 64; o <<= 1) { sum += __shfl_xor(sum, o); sq += __shfl_xor(sq, o); }
      float m = sum * (1.f / 512.f);
      float rstd = rsqrtf(sq * (1.f / 512.f) - m * m + 1e-5f);
      float4 c0, c1;
      c0.x = fminf(fmaxf((v0.x - m) * rstd * cga.x + cba.x, -10.f), 10.f);
      c0.y = fminf(fmaxf((v0.y - m) * rstd * cga.y + cba.y, -10.f), 10.f);
      c0.z = fminf(fmaxf((v0.z - m) * rstd * cga.z + cba.z, -10.f), 10.f);
      c0.w = fminf(fmaxf((v0.w - m) * rstd * cga.w + cba.w, -10.f), 10.f);
      c1.x = fminf(fmaxf((v1.x - m) * rstd * cgb.x + cbb.x, -10.f), 10.f);
      c1.y = fminf(fmaxf((v1.y - m) * rstd * cgb.y + cbb.y, -10.f), 10.f);
      c1.z = fminf(fmaxf((v1.z - m) * rstd * cgb.z + cbb.z, -10.f), 10.f);
      c1.w = fminf(fmaxf((v1.w - m) * rstd * cgb.w + cbb.w, -10.f), 10.f);
      *(float4*)(ctxn + gg * 512 + l8) = c0;
      *(float4*)(ctxn + gg * 512 + l8 + 4) = c1;
      if (wid == ((t - 1) & 127)) {   // round-robin traj writer (all WGs have full ctxn)
        float* tr = traj + (size_t)(gg * 512 + (t - 1)) * 512 + l8;
        st_f32x2(tr,     c0.x, c0.y);
        st_f32x2(tr + 2, c0.z, c0.w);
        st_f32x2(tr + 4, c1.x, c1.y);
        st_f32x2(tr + 6, c1.z, c1.w);
      }
    } else {
      float4 z = {0.f, 0.f, 0.f, 0.f};
      *(float4*)(ctxn + gg * 512 + l8) = z;
      *(float4*)(ctxn + gg * 512 + l8 + 4) = z;
    }
    __syncthreads();

    { // dots: groups 0-7 -> h1 col wid*8+g ; groups 8-15 -> gate/cand ctx col
      const float* wsl = (g < 8) ? (w1 + g * 512) : (wgc + (g - 8) * 512);
      float acc[8] = {0.f, 0.f, 0.f, 0.f, 0.f, 0.f, 0.f, 0.f};
      #pragma unroll
      for (int i = 0; i < 4; i++) {
        int kb = (s << 2) + (i << 7);
        float4 wv = *(const float4*)(wsl + kb);
        #pragma unroll
        for (int r = 0; r < 8; r++) {
          float4 cv = *(const float4*)(ctxn + r * 512 + kb);
          acc[r] += cv.x * wv.x + cv.y * wv.y + cv.z * wv.z + cv.w * wv.w;
        }
      }
      #pragma unroll
      for (int r = 0; r < 8; r++) {
        float v = acc[r];
        v += __shfl_xor(v, 1);  v += __shfl_xor(v, 2);  v += __shfl_xor(v, 4);
        v += __shfl_xor(v, 8);  v += __shfl_xor(v, 16);
        acc[r] = v;
      }
      if (s < 8) {
        if (g < 8) st_f32(&h1_wr[s * 1024 + (wid << 3) + g], fmaxf(pre1v + acc[s], 0.f));
        else       gcc[(g - 8) * 8 + s] = acc[s];
      }
    }
    db_post(db_h1, wid, (u32)(t + 1));

    // ===== phase 2: wait h1(t); h2 = relu(h1 @ W2 + b2) =====
    db_wait(db_h1, (u32)(t + 1));
    #pragma unroll
    for (int j = 0; j < 4; j++) {
      int idx = (tid + j * 512) << 2;
      *(float4*)(hst + idx) = *(const float4*)(h1_rd + idx);
    }
    __syncthreads();
    {
      const float* wsl = w2 + gg * 1024;
      float acc[8] = {0.f, 0.f, 0.f, 0.f, 0.f, 0.f, 0.f, 0.f};
      #pragma unroll
      for (int i = 0; i < 4; i++) {
        int kb = (l << 2) + (i << 8);
        float4 wv = *(const float4*)(wsl + kb);
        #pragma unroll
        for (int r = 0; r < 8; r++) {
          float4 hv = *(const float4*)(hst + r * 1024 + kb);
          acc[r] += hv.x * wv.x + hv.y * wv.y + hv.z * wv.z + hv.w * wv.w;
        }
      }
      #pragma unroll
      for (int r = 0; r < 8; r++) {
        float v = acc[r];
        v += __shfl_xor(v, 1);  v += __shfl_xor(v, 2);  v += __shfl_xor(v, 4);
        v += __shfl_xor(v, 8);  v += __shfl_xor(v, 16); v += __shfl_xor(v, 32);
        acc[r] = v;
      }
      if (l < 8) {
        int col = (wid << 3) + gg;
        float h = fmaxf(acc[l] + b2j, 0.f);
        st_f32(&h2_wr[l * 1024 + col], h);
        st_u16(&h2all[(size_t)((t << 3) + l) * 1024 + col], f2bf(h));
      }
    }
    db_post(db_h2, wid, (u32)(t + 1));

    // ===== phase 3: wait h2(t); gate/cand h2 dots; blend; store ctx(t+1) =====
    db_wait(db_h2, (u32)(t + 1));
    #pragma unroll
    for (int j = 0; j < 4; j++) {
      int idx = (tid + j * 512) << 2;
      *(float4*)(hst + idx) = *(const float4*)(h2_rd + idx);
    }
    __syncthreads();
    {
      const float* wsl = wgh + gg * 1024;   // 0-3 gate col wid*4+gg, 4-7 cand
      float acc[8] = {0.f, 0.f, 0.f, 0.f, 0.f, 0.f, 0.f, 0.f};
      #pragma unroll
      for (int i = 0; i < 4; i++) {
        int kb = (l << 2) + (i << 8);
        float4 wv = *(const float4*)(wsl + kb);
        #pragma unroll
        for (int r = 0; r < 8; r++) {
          float4 hv = *(const float4*)(hst + r * 1024 + kb);
          acc[r] += hv.x * wv.x + hv.y * wv.y + hv.z * wv.z + hv.w * wv.w;
        }
      }
      #pragma unroll
      for (int r = 0; r < 8; r++) {
        float v = acc[r];
        v += __shfl_xor(v, 1);  v += __shfl_xor(v, 2);  v += __shfl_xor(v, 4);
        v += __shfl_xor(v, 8);  v += __shfl_xor(v, 16); v += __shfl_xor(v, 32);
        acc[r] = v;
      }
      if (l < 8) pscr[gg * 8 + l] = acc[l];
    }
    __syncthreads();
    if (tid < 32) {
      int c = tid >> 3, r = tid & 7, j = (wid << 2) + c;
      float gd = pscr[c * 8 + r]       + gcc[c * 8 + r]       + bgj;
      float cd = pscr[(4 + c) * 8 + r] + gcc[(4 + c) * 8 + r] + bcj;
      float gate = 1.f / (1.f + __expf(-gd));
      float cand = tanhf(cd);
      st_f32(&ctx_wr[r * 512 + j], gate * cand + (1.f - gate) * ctxn[r * 512 + j]);
    }
    db_post(db_ctx, wid, (u32)(t + 1));
  }

  // final traj row (t = 511): ctx(512) lives in buffer 0, tagged 512
  if (wid == 0) {
    db_wait(db_ctx, 512u);
    const float* pr = pre_ctx + gg * 512 + l8;   // buffer 0
    float4 v0 = *(const float4*)pr;
    float4 v1 = *(const float4*)(pr + 4);
    float sum = v0.x + v0.y + v0.z + v0.w + v1.x + v1.y + v1.z + v1.w;
    float sq  = v0.x*v0.x + v0.y*v0.y + v0.z*v0.z + v0.w*v0.w
              + v1.x*v1.x + v1.y*v1.y + v1.z*v1.z + v1.w*v1.w;
    #pragma unroll
    for (int o = 1; o < 64; o <<= 1) { sum += __shfl_xor(sum, o); sq += __shfl_xor(sq, o); }
    float m = sum * (1.f / 512.f);
    float rstd = rsqrtf(sq * (1.f / 512.f) - m * m + 1e-5f);
    float4 c0, c1;
    c0.x = fminf(fmaxf((v0.x - m) * rstd * cga.x + cba.x, -10.f), 10.f);
    c0.y = fminf(fmaxf((v0.y - m) * rstd * cga.y + cba.y, -10.f), 10.f);
    c0.z = fminf(fmaxf((v0.z - m) * rstd * cga.z + cba.z, -10.f), 10.f);
    c0.w = fminf(fmaxf((v0.w - m) * rstd * cga.w + cba.w, -10.f), 10.f);
    c1.x = fminf(fmaxf((v1.x - m) * rstd * cgb.x + cbb.x, -10.f), 10.f);
    c1.y = fminf(fmaxf((v1.y - m) * rstd * cgb.y + cbb.y, -10.f), 10.f);
    c1.z = fminf(fmaxf((v1.z - m) * rstd * cgb.z + cbb.z, -10.f), 10.f);
    c1.w = fminf(fmaxf((v1.w - m) * rstd * cgb.w + cbb.w, -10.f), 10.f);
    float* tr = traj + (size_t)(gg * 512 + 511) * 512 + l8;
    *(float4*)tr = c0; *(float4*)(tr + 4) = c1;   // plain; end-of-kernel writeback
  }
}

// ---------------- launch ----------------
extern "C" void kernel_launch(void* const* d_in, const int* in_sizes, int n_in,
                              void* d_out, int out_size, void* d_ws, size_t ws_size,
                              hipStream_t stream) {
  const int*   ids  = (const int*)  d_in[0];
  const float* emb  = (const float*)d_in[1];
  const float* embg = (const float*)d_in[2];
  const float* embb = (const float*)d_in[3];
  const float* W1   = (const float*)d_in[4];
  const float* b1   = (const float*)d_in[5];
  const float* W2   = (const float*)d_in[6];
  const float* b2   = (const float*)d_in[7];
  const float* Wout = (const float*)d_in[8];
  const float* bout = (const float*)d_in[9];
  const float* Wg   = (const float*)d_in[10];
  const float* bg   = (const float*)d_in[11];
  const float* Wc   = (const float*)d_in[12];
  const float* bc   = (const float*)d_in[13];
  const float* cng  = (const float*)d_in[14];
  const float* cnb  = (const float*)d_in[15];

  float* out  = (float*)d_out;
  float* traj = out + (size_t)131072000;   // logits [8,512,32000] then traj [8,512,512]

  char* ws = (char*)d_ws;
  // persistent through logits GEMM:
  u16*   WoutT  = (u16*)(ws);                      // [32000][1024] bf16   65,536,000 B
  // early region (tokf/W1xT) later reused by scan weights:
  float* tokf   = (float*)(ws + 65536000);         // [4096][512] f32
  float* W1xT   = (float*)(ws + 73924608);         // [1024][512] f32
  float* pre1   = (float*)(ws + 76021760);         // [4096][1024] f32
  u16*   h2all  = (u16*)(ws + 92798976);           // [4096][1024] bf16
  // scan weights overlaid on tokf/W1xT region (dead after pre1 GEMM):
  float* W1cT   = (float*)(ws + 65536000);         // [1024][512]  2 MB
  float* W2T    = (float*)(ws + 67633152);         // [1024][1024] 4 MB
  float* WgcT   = (float*)(ws + 71827456);         // [512][512]   1 MB
  float* WccT   = (float*)(ws + 73924608);         // [512][512]   1 MB (over W1xT)
  float* WghT   = (float*)(ws + 101187584);        // [512][1024]  2 MB
  float* WchT   = (float*)(ws + 103284736);        // [512][1024]  2 MB
  float* h1f    = (float*)(ws + 105381888);        // [2][8][1024] 64 KB
  float* h2f    = (float*)(ws + 105447424);        // [2][8][1024] 64 KB
  float* prectx = (float*)(ws + 105512960);        // [2][8][512]  32 KB
  u32*   db     = (u32*)(ws + 105545728);          // doorbells (3 x 128 u32)

  // zero doorbells (tags are monotonic per-run; memset is part of the graph)
  hipMemsetAsync(db, 0, 4096, stream);

  // ---- stage A: logits weight transpose (bf16) + x-path in f32 ----
  k_transpose<<<dim3(16, 500), dim3(256), 0, stream>>>(Wout, WoutT, 1024, 32000, 32000);
  k_transpose_f32<<<dim3(8, 16), dim3(256), 0, stream>>>(W1, W1xT, 512, 1024, 1024);
  k_embed_f32<<<dim3(4096), dim3(256), 0, stream>>>(ids, emb, embg, embb, tokf);
  k_gemm_f32<<<dim3(64, 16), dim3(256), 0, stream>>>(tokf, W1xT, b1, pre1, 512, 1024);

  // ---- stage B: scan weight transposes (f32), overlaying tokf/W1xT ----
  k_transpose_f32<<<dim3(8, 16), dim3(256), 0, stream>>>(W1 + 512 * 1024, W1cT, 512, 1024, 1024);
  k_transpose_f32<<<dim3(16, 16), dim3(256), 0, stream>>>(W2, W2T, 1024, 1024, 1024);
  k_transpose_f32<<<dim3(8, 8), dim3(256), 0, stream>>>(Wg + 1024 * 512, WgcT, 512, 512, 512);
  k_transpose_f32<<<dim3(8, 8), dim3(256), 0, stream>>>(Wc + 1024 * 512, WccT, 512, 512, 512);
  k_transpose_f32<<<dim3(16, 8), dim3(256), 0, stream>>>(Wg, WghT, 1024, 512, 512);
  k_transpose_f32<<<dim3(16, 8), dim3(256), 0, stream>>>(Wc, WchT, 1024, 512, 512);

  // ---- stage C: dataflow f32 scan (LDS weights, doorbells + double buffer) ----
  hipFuncSetAttribute(reinterpret_cast<const void*>(k_scan),
                      hipFuncAttributeMaxDynamicSharedMemorySize, SMEM_SCAN);
  void* args[] = {(void*)&W1cT, (void*)&W2T, (void*)&WgcT, (void*)&WccT,
                  (void*)&WghT, (void*)&WchT, (void*)&b2, (void*)&bg, (void*)&bc,
                  (void*)&cng, (void*)&cnb, (void*)&pre1, (void*)&h1f, (void*)&h2f,
                  (void*)&prectx, (void*)&h2all, (void*)&traj, (void*)&db};
  hipLaunchCooperativeKernel((void*)k_scan, dim3(128), dim3(512), args, SMEM_SCAN, stream);

  // ---- stage D: logits ----
  k_gemm_logits<<<dim3(32, 250), dim3(256), 0, stream>>>(h2all, WoutT, bout, out, 1024);
}

// Round 10
// 7192.351 us; speedup vs baseline: 1.4735x; 1.4735x over previous
//
#include <hip/hip_runtime.h>

typedef unsigned short u16;
typedef unsigned int u32;
typedef unsigned long long u64;
typedef __attribute__((ext_vector_type(8))) short bf16x8;
typedef __attribute__((ext_vector_type(4))) float f32x4;

#define SMEM_SCAN 147968

__device__ __forceinline__ u16 f2bf(float f) {
  u32 u = __float_as_uint(f);
  u += 0x7fffu + ((u >> 16) & 1u);
  return (u16)(u >> 16);
}

__device__ __forceinline__ void async16(const void* g, void* l) {
  __builtin_amdgcn_global_load_lds((const __attribute__((address_space(1))) void*)g,
                                   (__attribute__((address_space(3))) void*)l, 16, 0, 0);
}

// relaxed agent-scope write-through stores: visible at coherence point once
// vmcnt drains (at __syncthreads), never leave dirty L2 lines.
__device__ __forceinline__ void st_f32(float* p, float v) {
  __hip_atomic_store(p, v, __ATOMIC_RELAXED, __HIP_MEMORY_SCOPE_AGENT);
}
__device__ __forceinline__ void st_u16(u16* p, u16 v) {
  __hip_atomic_store(p, v, __ATOMIC_RELAXED, __HIP_MEMORY_SCOPE_AGENT);
}
__device__ __forceinline__ void st_f32x2(float* p, float a, float b) {
  u64 v = ((u64)__float_as_uint(b) << 32) | (u64)__float_as_uint(a);
  __hip_atomic_store((u64*)p, v, __ATOMIC_RELAXED, __HIP_MEMORY_SCOPE_AGENT);
}

// ---------------- tag-based producer->consumer sync ----------------
// Post: __syncthreads drains this WG's write-through data stores to the
// coherence point, then tid0 write-through-stores tg[wid]=tag. Tags monotonic.
// Wait: wave 0 polls all 128 tags with CACHED loads, re-invalidating via one
// acquire fence (buffer_inv) per iteration. Cached polls dedupe in L2 MSHRs
// across co-XCD WGs (fixes r9's uncached-poll TCC contention). Monotonic tags
// + producer data-before-tag drain => any post-fence read seeing tag>=target
// implies data lines at L3 are fresh; all data fills are post-verification,
// so plain cached data reads after the exit __syncthreads are correct.
__device__ __forceinline__ void tag_post(u32* tg, int wid, u32 tag) {
  __syncthreads();   // all waves' data stores at coherence point
  if (threadIdx.x == 0)
    __hip_atomic_store(tg + wid, tag, __ATOMIC_RELAXED, __HIP_MEMORY_SCOPE_AGENT);
}
__device__ __forceinline__ void tag_wait(const u32* tg, u32 tag) {
  if (threadIdx.x < 64) {
    const volatile u32* a0 = tg + threadIdx.x;
    const volatile u32* a1 = tg + 64 + threadIdx.x;
    for (;;) {
      __builtin_amdgcn_fence(__ATOMIC_ACQUIRE, "agent");  // buffer_inv (L1+L2)
      u32 v0 = *a0;
      u32 v1 = *a1;
      if (__all((v0 >= tag) && (v1 >= tag))) break;
      __builtin_amdgcn_s_sleep(1);
    }
  }
  __syncthreads();   // waves 1-7 read only after wave0's fence
}

// ---------------- embedding gather + LayerNorm -> f32 ----------------
__global__ void __launch_bounds__(256)
k_embed_f32(const int* __restrict__ ids, const float* __restrict__ emb,
            const float* __restrict__ g, const float* __restrict__ b, float* __restrict__ tok) {
  int r = blockIdx.x;            // r = t*8 + batch
  int s = r >> 3, bch = r & 7;
  int id = ids[bch * 512 + s];
  const float* row = emb + (size_t)id * 512;
  int tid = threadIdx.x;
  float2 v = *(const float2*)&row[tid * 2];
  float sum = v.x + v.y, sq = v.x * v.x + v.y * v.y;
  #pragma unroll
  for (int o = 1; o < 64; o <<= 1) { sum += __shfl_xor(sum, o); sq += __shfl_xor(sq, o); }
  __shared__ float rs[4][2];
  int w = tid >> 6;
  if ((tid & 63) == 0) { rs[w][0] = sum; rs[w][1] = sq; }
  __syncthreads();
  float S = rs[0][0] + rs[1][0] + rs[2][0] + rs[3][0];
  float Q = rs[0][1] + rs[1][1] + rs[2][1] + rs[3][1];
  float m = S * (1.f / 512.f);
  float rstd = rsqrtf(Q * (1.f / 512.f) - m * m + 1e-5f);
  int e = tid * 2;
  float2 o2;
  o2.x = (v.x - m) * rstd * g[e] + b[e];
  o2.y = (v.y - m) * rstd * g[e + 1] + b[e + 1];
  *(float2*)&tok[(size_t)r * 512 + e] = o2;
}

// ---------------- f32 [K][N] -> bf16 [N][K] transpose-convert ----------------
__global__ void __launch_bounds__(256)
k_transpose(const float* __restrict__ src, u16* __restrict__ dst,
            int K, int N, int stride) {
  __shared__ float tl[64][65];
  int k0 = blockIdx.x << 6, n0 = blockIdx.y << 6;
  int tid = threadIdx.x;
  int a = tid >> 6, c = tid & 63;
  #pragma unroll
  for (int p = 0; p < 64; p += 4)
    tl[p + a][c] = src[(size_t)(k0 + p + a) * stride + n0 + c];
  __syncthreads();
  #pragma unroll
  for (int p = 0; p < 64; p += 4)
    dst[(size_t)(n0 + p + a) * K + k0 + c] = f2bf(tl[c][p + a]);
}

// ---------------- f32 [K][N] -> f32 [N][K] transpose ----------------
__global__ void __launch_bounds__(256)
k_transpose_f32(const float* __restrict__ src, float* __restrict__ dst,
                int K, int N, int stride) {
  __shared__ float tl[64][65];
  int k0 = blockIdx.x << 6, n0 = blockIdx.y << 6;
  int tid = threadIdx.x;
  int a = tid >> 6, c = tid & 63;
  #pragma unroll
  for (int p = 0; p < 64; p += 4)
    tl[p + a][c] = src[(size_t)(k0 + p + a) * stride + n0 + c];
  __syncthreads();
  #pragma unroll
  for (int p = 0; p < 64; p += 4)
    dst[(size_t)(n0 + p + a) * K + k0 + c] = tl[c][p + a];
}

// ---------------- naive f32 tiled GEMM: C[m][n] = A[m]·BT[n] + bias[n] ----------------
__global__ void __launch_bounds__(256)
k_gemm_f32(const float* __restrict__ A, const float* __restrict__ BT,
           const float* __restrict__ bias, float* __restrict__ C, int K, int N) {
  __shared__ float Atl[64][17];
  __shared__ float Btl[64][17];
  int tid = threadIdx.x;
  int m0 = blockIdx.x << 6, n0 = blockIdx.y << 6;
  int lr = tid >> 2, lk = (tid & 3) << 2;
  int tm = (tid >> 4) << 2, tn = (tid & 15) << 2;
  float acc[4][4] = {{0.f}};
  for (int k0 = 0; k0 < K; k0 += 16) {
    float4 av = *(const float4*)&A[(size_t)(m0 + lr) * K + k0 + lk];
    float4 bv = *(const float4*)&BT[(size_t)(n0 + lr) * K + k0 + lk];
    __syncthreads();
    Atl[lr][lk] = av.x; Atl[lr][lk + 1] = av.y; Atl[lr][lk + 2] = av.z; Atl[lr][lk + 3] = av.w;
    Btl[lr][lk] = bv.x; Btl[lr][lk + 1] = bv.y; Btl[lr][lk + 2] = bv.z; Btl[lr][lk + 3] = bv.w;
    __syncthreads();
    #pragma unroll
    for (int kk = 0; kk < 16; kk++) {
      float a0 = Atl[tm][kk], a1 = Atl[tm + 1][kk], a2 = Atl[tm + 2][kk], a3 = Atl[tm + 3][kk];
      float b0 = Btl[tn][kk], b1 = Btl[tn + 1][kk], b2 = Btl[tn + 2][kk], b3 = Btl[tn + 3][kk];
      acc[0][0] += a0 * b0; acc[0][1] += a0 * b1; acc[0][2] += a0 * b2; acc[0][3] += a0 * b3;
      acc[1][0] += a1 * b0; acc[1][1] += a1 * b1; acc[1][2] += a1 * b2; acc[1][3] += a1 * b3;
      acc[2][0] += a2 * b0; acc[2][1] += a2 * b1; acc[2][2] += a2 * b2; acc[2][3] += a2 * b3;
      acc[3][0] += a3 * b0; acc[3][1] += a3 * b1; acc[3][2] += a3 * b2; acc[3][3] += a3 * b3;
    }
  }
  #pragma unroll
  for (int a = 0; a < 4; a++)
    #pragma unroll
    for (int b = 0; b < 4; b++)
      C[(size_t)(m0 + tm + a) * N + n0 + tn + b] = acc[a][b] + bias[n0 + tn + b];
}

// ---------------- bf16 MFMA GEMM (logits): C = A[M,K] @ B[N,K]^T + bias, remapped ----------------
__global__ void __launch_bounds__(256)
k_gemm_logits(const u16* __restrict__ A, const u16* __restrict__ B,
              const float* __restrict__ bias, float* __restrict__ C, int K) {
  __shared__ u16 As[128 * 32];
  __shared__ u16 Bs[128 * 32];
  int tid = threadIdx.x;
  int w = tid >> 6, l = tid & 63;
  int m0 = blockIdx.x * 128, n0 = blockIdx.y * 128;
  const u16* pA0 = A + (size_t)(m0 + w * 32 + (l >> 2)) * K + (l & 3) * 8;
  const u16* pB0 = B + (size_t)(n0 + w * 32 + (l >> 2)) * K + (l & 3) * 8;
  u16* lA0 = As + w * 1024;
  u16* lB0 = Bs + w * 1024;

  f32x4 acc[4][4];
  #pragma unroll
  for (int i = 0; i < 4; i++)
    #pragma unroll
    for (int j = 0; j < 4; j++) { f32x4 z = {0.f, 0.f, 0.f, 0.f}; acc[i][j] = z; }

  #pragma unroll 1
  for (int k0 = 0; k0 < K; k0 += 32) {
    async16(pA0, lA0);
    async16(pA0 + 16 * K, lA0 + 512);
    async16(pB0, lB0);
    async16(pB0 + 16 * K, lB0 + 512);
    pA0 += 32; pB0 += 32;
    __syncthreads();
    bf16x8 a[4], b[4];
    #pragma unroll
    for (int i = 0; i < 4; i++)
      a[i] = *(const bf16x8*)(As + ((w & 1) * 64 + i * 16 + (l & 15)) * 32 + (l >> 4) * 8);
    #pragma unroll
    for (int j = 0; j < 4; j++)
      b[j] = *(const bf16x8*)(Bs + ((w >> 1) * 64 + j * 16 + (l & 15)) * 32 + (l >> 4) * 8);
    #pragma unroll
    for (int i = 0; i < 4; i++)
      #pragma unroll
      for (int j = 0; j < 4; j++)
        acc[i][j] = __builtin_amdgcn_mfma_f32_16x16x32_bf16(a[i], b[j], acc[i][j], 0, 0, 0);
    __syncthreads();
  }

  #pragma unroll
  for (int j = 0; j < 4; j++) {
    int gn = n0 + (w >> 1) * 64 + j * 16 + (l & 15);
    float bj = bias[gn];
    #pragma unroll
    for (int i = 0; i < 4; i++) {
      int gmB = m0 + (w & 1) * 64 + i * 16 + (l >> 4) * 4;
      #pragma unroll
      for (int e = 0; e < 4; e++) {
        int gm = gmB + e;   // gm = t*8 + b  ->  logits[(b*512 + t)*32000 + gn]
        C[(size_t)((gm & 7) * 512 + (gm >> 3)) * 32000 + gn] = acc[i][j][e] + bj;
      }
    }
  }
}

// ---------------- persistent dataflow recurrence kernel ----------------
// 128 WGs x 512 threads, 1 WG/CU, LDS-resident f32 weights. Cross-WG state
// double-buffered (products of step t in buffer t&1); sync = per-phase tags
// (tg_h1/tg_h2/tg_ctx, tag = t+1) with cached-poll + per-iter acquire fence.
__global__ void __launch_bounds__(512)
k_scan(const float* __restrict__ W1cT, const float* __restrict__ W2T,
       const float* __restrict__ WgcT, const float* __restrict__ WccT,
       const float* __restrict__ WghT, const float* __restrict__ WchT,
       const float* __restrict__ b2v, const float* __restrict__ bgv,
       const float* __restrict__ bcv, const float* __restrict__ cng,
       const float* __restrict__ cnb, const float* __restrict__ pre1,
       float* __restrict__ h1f, float* __restrict__ h2f,
       float* __restrict__ pre_ctx, u16* __restrict__ h2all,
       float* __restrict__ traj, u32* __restrict__ db) {
  extern __shared__ float smem[];
  float* w1   = smem;                 // [8][512]  h1 cols wid*8+g           (16 KB)
  float* wgc  = w1 + 4096;            // [8][512]  0-3 gate / 4-7 cand ctx   (16 KB)
  float* w2   = wgc + 4096;           // [8][1024] W2 cols wid*8+g           (32 KB)
  float* wgh  = w2 + 8192;            // [8][1024] 0-3 gate / 4-7 cand h2    (32 KB)
  float* ctxn = wgh + 8192;           // [8][512]  normalized ctx            (16 KB)
  float* hst  = ctxn + 4096;          // [8][1024] staged h1 / h2            (32 KB)
  float* gcc  = hst + 8192;           // [8][8]    ctx-part gate/cand dots
  float* pscr = gcc + 64;             // [8][8]    h2-part gate/cand dots

  u32* tg_h1  = db;
  u32* tg_h2  = db + 128;
  u32* tg_ctx = db + 256;

  const int tid = threadIdx.x;
  const int wid = blockIdx.x;
  const int g   = tid >> 5;           // phase-1 group 0..15
  const int s   = tid & 31;
  const int gg  = tid >> 6;           // phase-2/3 group 0..7
  const int l   = tid & 63;

  // ---- one-time weight preload into LDS (all contiguous f32 slices) ----
  {
    const float4* srcs[6] = {
      (const float4*)(W1cT + (size_t)wid * 4096),
      (const float4*)(WgcT + (size_t)wid * 2048),
      (const float4*)(WccT + (size_t)wid * 2048),
      (const float4*)(W2T  + (size_t)wid * 8192),
      (const float4*)(WghT + (size_t)wid * 4096),
      (const float4*)(WchT + (size_t)wid * 4096)};
    float4* dsts[6] = {(float4*)w1, (float4*)wgc, (float4*)(wgc + 2048),
                       (float4*)w2, (float4*)wgh, (float4*)(wgh + 4096)};
    const int n4[6] = {1024, 512, 512, 2048, 1024, 1024};
    #pragma unroll
    for (int q = 0; q < 6; q++)
      for (int i = tid; i < n4[q]; i += 512) dsts[q][i] = srcs[q][i];
  }

  // ---- per-thread constant preloads ----
  const int l8 = l * 8;
  const float4 cga = *(const float4*)&cng[l8];
  const float4 cgb = *(const float4*)&cng[l8 + 4];
  const float4 cba = *(const float4*)&cnb[l8];
  const float4 cbb = *(const float4*)&cnb[l8 + 4];
  const float b2j = b2v[(wid << 3) + gg];
  float bgj = 0.f, bcj = 0.f;
  if (tid < 32) {
    int j = (wid << 2) + (tid >> 3);
    bgj = bgv[j]; bcj = bcv[j];
  }
  __syncthreads();

  #pragma unroll 1
  for (int t = 0; t < 512; ++t) {
    const float* ctx_rd = pre_ctx + (t & 1) * 4096;        // ctx for step t
    float*       ctx_wr = pre_ctx + ((t + 1) & 1) * 4096;  // ctx for step t+1
    const float* h1_rd  = h1f + (t & 1) * 8192;
    float*       h1_wr  = h1f + (t & 1) * 8192;
    const float* h2_rd  = h2f + (t & 1) * 8192;
    float*       h2_wr  = h2f + (t & 1) * 8192;

    // prefetch pre1 (read-only input; safe to load pre-fence)
    float pre1v = 0.f;
    if (g < 8 && s < 8)
      pre1v = pre1[(size_t)((t << 3) + s) * 1024 + (wid << 3) + g];

    // ===== phase 1: wait ctx(t); LN -> ctxn (redundant per WG); h1 + gc_ctx dots =====
    if (t > 0) {
      tag_wait(tg_ctx, (u32)t);
      const float* pr = ctx_rd + gg * 512 + l8;   // wave gg handles row gg
      float4 v0 = *(const float4*)pr;
      float4 v1 = *(const float4*)(pr + 4);
      float sum = v0.x + v0.y + v0.z + v0.w + v1.x + v1.y + v1.z + v1.w;
      float sq  = v0.x*v0.x + v0.y*v0.y + v0.z*v0.z + v0.w*v0.w
                + v1.x*v1.x + v1.y*v1.y + v1.z*v1.z + v1.w*v1.w;
      #pragma unroll
      for (int o = 1; o < 64; o <<= 1) { sum += __shfl_xor(sum, o); sq += __shfl_xor(sq, o); }
      float m = sum * (1.f / 512.f);
      float rstd = rsqrtf(sq * (1.f / 512.f) - m * m + 1e-5f);
      float4 c0, c1;
      c0.x = fminf(fmaxf((v0.x - m) * rstd * cga.x + cba.x, -10.f), 10.f);
      c0.y = fminf(fmaxf((v0.y - m) * rstd * cga.y + cba.y, -10.f), 10.f);
      c0.z = fminf(fmaxf((v0.z - m) * rstd * cga.z + cba.z, -10.f), 10.f);
      c0.w = fminf(fmaxf((v0.w - m) * rstd * cga.w + cba.w, -10.f), 10.f);
      c1.x = fminf(fmaxf((v1.x - m) * rstd * cgb.x + cbb.x, -10.f), 10.f);
      c1.y = fminf(fmaxf((v1.y - m) * rstd * cgb.y + cbb.y, -10.f), 10.f);
      c1.z = fminf(fmaxf((v1.z - m) * rstd * cgb.z + cbb.z, -10.f), 10.f);
      c1.w = fminf(fmaxf((v1.w - m) * rstd * cgb.w + cbb.w, -10.f), 10.f);
      *(float4*)(ctxn + gg * 512 + l8) = c0;
      *(float4*)(ctxn + gg * 512 + l8 + 4) = c1;
      if (wid == ((t - 1) & 127)) {   // round-robin traj writer
        float* tr = traj + (size_t)(gg * 512 + (t - 1)) * 512 + l8;
        st_f32x2(tr,     c0.x, c0.y);
        st_f32x2(tr + 2, c0.z, c0.w);
        st_f32x2(tr + 4, c1.x, c1.y);
        st_f32x2(tr + 6, c1.z, c1.w);
      }
    } else {
      float4 z = {0.f, 0.f, 0.f, 0.f};
      *(float4*)(ctxn + gg * 512 + l8) = z;
      *(float4*)(ctxn + gg * 512 + l8 + 4) = z;
    }
    __syncthreads();

    { // dots: groups 0-7 -> h1 col wid*8+g ; groups 8-15 -> gate/cand ctx col
      const float* wsl = (g < 8) ? (w1 + g * 512) : (wgc + (g - 8) * 512);
      float acc[8] = {0.f, 0.f, 0.f, 0.f, 0.f, 0.f, 0.f, 0.f};
      #pragma unroll
      for (int i = 0; i < 4; i++) {
        int kb = (s << 2) + (i << 7);
        float4 wv = *(const float4*)(wsl + kb);
        #pragma unroll
        for (int r = 0; r < 8; r++) {
          float4 cv = *(const float4*)(ctxn + r * 512 + kb);
          acc[r] += cv.x * wv.x + cv.y * wv.y + cv.z * wv.z + cv.w * wv.w;
        }
      }
      #pragma unroll
      for (int r = 0; r < 8; r++) {
        float v = acc[r];
        v += __shfl_xor(v, 1);  v += __shfl_xor(v, 2);  v += __shfl_xor(v, 4);
        v += __shfl_xor(v, 8);  v += __shfl_xor(v, 16);
        acc[r] = v;
      }
      if (s < 8) {
        if (g < 8) st_f32(&h1_wr[s * 1024 + (wid << 3) + g], fmaxf(pre1v + acc[s], 0.f));
        else       gcc[(g - 8) * 8 + s] = acc[s];
      }
    }
    tag_post(tg_h1, wid, (u32)(t + 1));

    // ===== phase 2: wait h1(t); h2 = relu(h1 @ W2 + b2) =====
    tag_wait(tg_h1, (u32)(t + 1));
    #pragma unroll
    for (int j = 0; j < 4; j++) {
      int idx = (tid + j * 512) << 2;
      *(float4*)(hst + idx) = *(const float4*)(h1_rd + idx);
    }
    __syncthreads();
    float hkeep = 0.f;
    const int col2 = (wid << 3) + gg;
    {
      const float* wsl = w2 + gg * 1024;
      float acc[8] = {0.f, 0.f, 0.f, 0.f, 0.f, 0.f, 0.f, 0.f};
      #pragma unroll
      for (int i = 0; i < 4; i++) {
        int kb = (l << 2) + (i << 8);
        float4 wv = *(const float4*)(wsl + kb);
        #pragma unroll
        for (int r = 0; r < 8; r++) {
          float4 hv = *(const float4*)(hst + r * 1024 + kb);
          acc[r] += hv.x * wv.x + hv.y * wv.y + hv.z * wv.z + hv.w * wv.w;
        }
      }
      #pragma unroll
      for (int r = 0; r < 8; r++) {
        float v = acc[r];
        v += __shfl_xor(v, 1);  v += __shfl_xor(v, 2);  v += __shfl_xor(v, 4);
        v += __shfl_xor(v, 8);  v += __shfl_xor(v, 16); v += __shfl_xor(v, 32);
        acc[r] = v;
      }
      if (l < 8) {
        hkeep = fmaxf(acc[l] + b2j, 0.f);
        st_f32(&h2_wr[l * 1024 + col2], hkeep);
      }
    }
    tag_post(tg_h2, wid, (u32)(t + 1));
    // h2all store off the drain critical path (write-through; drains during polls)
    if (l < 8)
      st_u16(&h2all[(size_t)((t << 3) + l) * 1024 + col2], f2bf(hkeep));

    // ===== phase 3: wait h2(t); gate/cand h2 dots; blend; store ctx(t+1) =====
    tag_wait(tg_h2, (u32)(t + 1));
    #pragma unroll
    for (int j = 0; j < 4; j++) {
      int idx = (tid + j * 512) << 2;
      *(float4*)(hst + idx) = *(const float4*)(h2_rd + idx);
    }
    __syncthreads();
    {
      const float* wsl = wgh + gg * 1024;   // 0-3 gate col wid*4+gg, 4-7 cand
      float acc[8] = {0.f, 0.f, 0.f, 0.f, 0.f, 0.f, 0.f, 0.f};
      #pragma unroll
      for (int i = 0; i < 4; i++) {
        int kb = (l << 2) + (i << 8);
        float4 wv = *(const float4*)(wsl + kb);
        #pragma unroll
        for (int r = 0; r < 8; r++) {
          float4 hv = *(const float4*)(hst + r * 1024 + kb);
          acc[r] += hv.x * wv.x + hv.y * wv.y + hv.z * wv.z + hv.w * wv.w;
        }
      }
      #pragma unroll
      for (int r = 0; r < 8; r++) {
        float v = acc[r];
        v += __shfl_xor(v, 1);  v += __shfl_xor(v, 2);  v += __shfl_xor(v, 4);
        v += __shfl_xor(v, 8);  v += __shfl_xor(v, 16); v += __shfl_xor(v, 32);
        acc[r] = v;
      }
      if (l < 8) pscr[gg * 8 + l] = acc[l];
    }
    __syncthreads();
    if (tid < 32) {
      int c = tid >> 3, r = tid & 7, j = (wid << 2) + c;
      float gd = pscr[c * 8 + r]       + gcc[c * 8 + r]       + bgj;
      float cd = pscr[(4 + c) * 8 + r] + gcc[(4 + c) * 8 + r] + bcj;
      float gate = 1.f / (1.f + __expf(-gd));
      float cand = tanhf(cd);
      st_f32(&ctx_wr[r * 512 + j], gate * cand + (1.f - gate) * ctxn[r * 512 + j]);
    }
    tag_post(tg_ctx, wid, (u32)(t + 1));
  }

  // final traj row (t = 511): ctx(512) lives in buffer 0, tagged 512
  if (wid == 0) {
    tag_wait(tg_ctx, 512u);
    const float* pr = pre_ctx + gg * 512 + l8;   // buffer 0
    float4 v0 = *(const float4*)pr;
    float4 v1 = *(const float4*)(pr + 4);
    float sum = v0.x + v0.y + v0.z + v0.w + v1.x + v1.y + v1.z + v1.w;
    float sq  = v0.x*v0.x + v0.y*v0.y + v0.z*v0.z + v0.w*v0.w
              + v1.x*v1.x + v1.y*v1.y + v1.z*v1.z + v1.w*v1.w;
    #pragma unroll
    for (int o = 1; o < 64; o <<= 1) { sum += __shfl_xor(sum, o); sq += __shfl_xor(sq, o); }
    float m = sum * (1.f / 512.f);
    float rstd = rsqrtf(sq * (1.f / 512.f) - m * m + 1e-5f);
    float4 c0, c1;
    c0.x = fminf(fmaxf((v0.x - m) * rstd * cga.x + cba.x, -10.f), 10.f);
    c0.y = fminf(fmaxf((v0.y - m) * rstd * cga.y + cba.y, -10.f), 10.f);
    c0.z = fminf(fmaxf((v0.z - m) * rstd * cga.z + cba.z, -10.f), 10.f);
    c0.w = fminf(fmaxf((v0.w - m) * rstd * cga.w + cba.w, -10.f), 10.f);
    c1.x = fminf(fmaxf((v1.x - m) * rstd * cgb.x + cbb.x, -10.f), 10.f);
    c1.y = fminf(fmaxf((v1.y - m) * rstd * cgb.y + cbb.y, -10.f), 10.f);
    c1.z = fminf(fmaxf((v1.z - m) * rstd * cgb.z + cbb.z, -10.f), 10.f);
    c1.w = fminf(fmaxf((v1.w - m) * rstd * cgb.w + cbb.w, -10.f), 10.f);
    float* tr = traj + (size_t)(gg * 512 + 511) * 512 + l8;
    st_f32x2(tr,     c0.x, c0.y);
    st_f32x2(tr + 2, c0.z, c0.w);
    st_f32x2(tr + 4, c1.x, c1.y);
    st_f32x2(tr + 6, c1.z, c1.w);
  }
}

// ---------------- launch ----------------
extern "C" void kernel_launch(void* const* d_in, const int* in_sizes, int n_in,
                              void* d_out, int out_size, void* d_ws, size_t ws_size,
                              hipStream_t stream) {
  const int*   ids  = (const int*)  d_in[0];
  const float* emb  = (const float*)d_in[1];
  const float* embg = (const float*)d_in[2];
  const float* embb = (const float*)d_in[3];
  const float* W1   = (const float*)d_in[4];
  const float* b1   = (const float*)d_in[5];
  const float* W2   = (const float*)d_in[6];
  const float* b2   = (const float*)d_in[7];
  const float* Wout = (const float*)d_in[8];
  const float* bout = (const float*)d_in[9];
  const float* Wg   = (const float*)d_in[10];
  const float* bg   = (const float*)d_in[11];
  const float* Wc   = (const float*)d_in[12];
  const float* bc   = (const float*)d_in[13];
  const float* cng  = (const float*)d_in[14];
  const float* cnb  = (const float*)d_in[15];

  float* out  = (float*)d_out;
  float* traj = out + (size_t)131072000;   // logits [8,512,32000] then traj [8,512,512]

  char* ws = (char*)d_ws;
  // persistent through logits GEMM:
  u16*   WoutT  = (u16*)(ws);                      // [32000][1024] bf16   65,536,000 B
  // early region (tokf/W1xT) later reused by scan weights:
  float* tokf   = (float*)(ws + 65536000);         // [4096][512] f32
  float* W1xT   = (float*)(ws + 73924608);         // [1024][512] f32
  float* pre1   = (float*)(ws + 76021760);         // [4096][1024] f32
  u16*   h2all  = (u16*)(ws + 92798976);           // [4096][1024] bf16
  // scan weights overlaid on tokf/W1xT region (dead after pre1 GEMM):
  float* W1cT   = (float*)(ws + 65536000);         // [1024][512]  2 MB
  float* W2T    = (float*)(ws + 67633152);         // [1024][1024] 4 MB
  float* WgcT   = (float*)(ws + 71827456);         // [512][512]   1 MB
  float* WccT   = (float*)(ws + 73924608);         // [512][512]   1 MB (over W1xT)
  float* WghT   = (float*)(ws + 101187584);        // [512][1024]  2 MB
  float* WchT   = (float*)(ws + 103284736);        // [512][1024]  2 MB
  float* h1f    = (float*)(ws + 105381888);        // [2][8][1024] 64 KB
  float* h2f    = (float*)(ws + 105447424);        // [2][8][1024] 64 KB
  float* prectx = (float*)(ws + 105512960);        // [2][8][512]  32 KB
  u32*   db     = (u32*)(ws + 105545728);          // tags (3 x 128 u32)

  // zero tags (monotonic per-run; memset is part of the graph)
  hipMemsetAsync(db, 0, 4096, stream);

  // ---- stage A: logits weight transpose (bf16) + x-path in f32 ----
  k_transpose<<<dim3(16, 500), dim3(256), 0, stream>>>(Wout, WoutT, 1024, 32000, 32000);
  k_transpose_f32<<<dim3(8, 16), dim3(256), 0, stream>>>(W1, W1xT, 512, 1024, 1024);
  k_embed_f32<<<dim3(4096), dim3(256), 0, stream>>>(ids, emb, embg, embb, tokf);
  k_gemm_f32<<<dim3(64, 16), dim3(256), 0, stream>>>(tokf, W1xT, b1, pre1, 512, 1024);

  // ---- stage B: scan weight transposes (f32), overlaying tokf/W1xT ----
  k_transpose_f32<<<dim3(8, 16), dim3(256), 0, stream>>>(W1 + 512 * 1024, W1cT, 512, 1024, 1024);
  k_transpose_f32<<<dim3(16, 16), dim3(256), 0, stream>>>(W2, W2T, 1024, 1024, 1024);
  k_transpose_f32<<<dim3(8, 8), dim3(256), 0, stream>>>(Wg + 1024 * 512, WgcT, 512, 512, 512);
  k_transpose_f32<<<dim3(8, 8), dim3(256), 0, stream>>>(Wc + 1024 * 512, WccT, 512, 512, 512);
  k_transpose_f32<<<dim3(16, 8), dim3(256), 0, stream>>>(Wg, WghT, 1024, 512, 512);
  k_transpose_f32<<<dim3(16, 8), dim3(256), 0, stream>>>(Wc, WchT, 1024, 512, 512);

  // ---- stage C: dataflow f32 scan (LDS weights, cached-poll tags + double buffer) ----
  hipFuncSetAttribute(reinterpret_cast<const void*>(k_scan),
                      hipFuncAttributeMaxDynamicSharedMemorySize, SMEM_SCAN);
  void* args[] = {(void*)&W1cT, (void*)&W2T, (void*)&WgcT, (void*)&WccT,
                  (void*)&WghT, (void*)&WchT, (void*)&b2, (void*)&bg, (void*)&bc,
                  (void*)&cng, (void*)&cnb, (void*)&pre1, (void*)&h1f, (void*)&h2f,
                  (void*)&prectx, (void*)&h2all, (void*)&traj, (void*)&db};
  hipLaunchCooperativeKernel((void*)k_scan, dim3(128), dim3(512), args, SMEM_SCAN, stream);

  // ---- stage D: logits ----
  k_gemm_logits<<<dim3(32, 250), dim3(256), 0, stream>>>(h2all, WoutT, bout, out, 1024);
}